// Round 15
// baseline (318.234 us; speedup 1.0000x reference)
//
#include <hip/hip_runtime.h>
#include <stdint.h>

// ---------------------------------------------------------------------------
// FalconMamba2 SSM decoder layer, MI355X (gfx950) — round 15
// in_proj: 192x128 single-buffered (40 KB LDS -> 4 blocks/CU; best LDS:MFMA
// ratio 1.03 AND high occupancy — first config with both). out_proj reverted
// to depth-3 pipeline (round-13 best). Everything else = round 14.
// ---------------------------------------------------------------------------

typedef __bf16 bf16x8 __attribute__((ext_vector_type(8)));
typedef float  f32x4  __attribute__((ext_vector_type(4)));

#define DEVFN __device__ __forceinline__

DEVFN unsigned short f2b(float f) {
  uint32_t u = __builtin_bit_cast(uint32_t, f);
  u += 0x7fffu + ((u >> 16) & 1u);          // round-to-nearest-even
  return (unsigned short)(u >> 16);
}
DEVFN float b2f(unsigned short u) {
  uint32_t x = (uint32_t)u << 16;
  return __builtin_bit_cast(float, x);
}
DEVFN bf16x8 pack8(const float (&m)[8]) {
  bf16x8 r;
#pragma unroll
  for (int t = 0; t < 8; ++t) r[t] = (__bf16)m[t];
  return r;
}

// bijective XCD swizzle (m204) + GROUP-major supertiling
DEVFN void tile_map(int bid, int nwg, int nm, int nn, int grp, int& mt, int& nt) {
  const int q = nwg >> 3, r = nwg & 7;
  const int xcd = bid & 7, lid = bid >> 3;
  const int wg = (xcd < r ? xcd * (q + 1) : r * (q + 1) + (xcd - r) * q) + lid;
  const int per = grp * nn;
  const int g = wg / per;
  const int rem = wg - g * per;
  const int lim = nm - g * grp;
  const int gm = lim < grp ? lim : grp;
  mt = g * grp + rem % gm;
  nt = rem / gm;
}

// ---------------------------------------------------------------------------
// prep: blocks [0, NCVT) convert both weight matrices fp32->bf16 (padded);
// blocks [NCVT, NCVT+2112) compute input RMSNorm rows (rows>=2048 zero-pad).
// ---------------------------------------------------------------------------
__global__ __launch_bounds__(256) void prep(
    const float* __restrict__ W_in, unsigned short* __restrict__ Wb_in,
    const float* __restrict__ W_out, unsigned short* __restrict__ Wb_out,
    const float* __restrict__ x, const float* __restrict__ rms_w,
    unsigned short* __restrict__ h, int ncvt) {
  const long d1 = (long)8576 * 2048, s1 = (long)8512 * 2048;
  const long d2 = (long)2048 * 4096;
  if (blockIdx.x < (unsigned)ncvt) {
    long i = ((long)blockIdx.x * 256 + threadIdx.x) * 4;
    const float* s; unsigned short* d; long srcE;
    if (i < d1) { s = W_in; d = Wb_in; srcE = s1; }
    else {
      i -= d1;
      if (i >= d2) return;
      s = W_out; d = Wb_out; srcE = d2;
    }
    ushort4 o;
    if (i < srcE) {
      float4 v = *reinterpret_cast<const float4*>(s + i);
      o.x = f2b(v.x); o.y = f2b(v.y); o.z = f2b(v.z); o.w = f2b(v.w);
    } else {
      o.x = 0; o.y = 0; o.z = 0; o.w = 0;
    }
    *reinterpret_cast<ushort4*>(d + i) = o;
    return;
  }
  // ---- RMSNorm rows
  const int row = blockIdx.x - ncvt;
  const int base = threadIdx.x * 8;
  if (row >= 2048) {
    ushort4 z = {0, 0, 0, 0};
    *reinterpret_cast<ushort4*>(h + (size_t)row * 2048 + base)     = z;
    *reinterpret_cast<ushort4*>(h + (size_t)row * 2048 + base + 4) = z;
    return;
  }
  const float* xr = x + (size_t)row * 2048;
  float4 v0 = *reinterpret_cast<const float4*>(xr + base);
  float4 v1 = *reinterpret_cast<const float4*>(xr + base + 4);
  float ss = v0.x*v0.x + v0.y*v0.y + v0.z*v0.z + v0.w*v0.w
           + v1.x*v1.x + v1.y*v1.y + v1.z*v1.z + v1.w*v1.w;
  __shared__ float red[4];
#pragma unroll
  for (int off = 32; off > 0; off >>= 1) ss += __shfl_xor(ss, off);
  if ((threadIdx.x & 63) == 0) red[threadIdx.x >> 6] = ss;
  __syncthreads();
  ss = red[0] + red[1] + red[2] + red[3];
  const float scale = rsqrtf(ss * (1.0f / 2048.0f) + 1e-5f);
  float vals[8] = {v0.x, v0.y, v0.z, v0.w, v1.x, v1.y, v1.z, v1.w};
  unsigned short o[8];
#pragma unroll
  for (int j = 0; j < 8; ++j) o[j] = f2b(vals[j] * scale * rms_w[base + j]);
  ushort4 a, b;
  a.x = o[0]; a.y = o[1]; a.z = o[2]; a.w = o[3];
  b.x = o[4]; b.y = o[5]; b.z = o[6]; b.w = o[7];
  *reinterpret_cast<ushort4*>(h + (size_t)row * 2048 + base)     = a;
  *reinterpret_cast<ushort4*>(h + (size_t)row * 2048 + base + 4) = b;
}

// ---------------------------------------------------------------------------
// Single-buffered high-occupancy bf16 GEMM — in_proj. BM x 128 tile, BK=64,
// 4 waves (2x2), XOR swizzle. BM=192: 40 KB LDS -> 4 blocks/CU; all 737
// blocks co-resident; cross-wave overlap hides barrier drain (m114).
// OUT16: C written bf16.
// ---------------------------------------------------------------------------
template<int BM, bool RES, bool OUT16>
__global__ __launch_bounds__(256, 4) void gemm_sb(
    const unsigned short* __restrict__ A, const unsigned short* __restrict__ B,
    void* __restrict__ Cv, const float* __restrict__ res,
    int K, int Mc, int Nc, int ldc, int nm, int nn, int grp) {
  constexpr int MF = BM / 32;
  __shared__ __align__(16) unsigned short As[BM * 64];
  __shared__ __align__(16) unsigned short Bs[128 * 64];
  int mt, nt;
  tile_map(blockIdx.x, nm * nn, nm, nn, grp, mt, nt);
  const int m0 = mt * BM;
  const int n0 = nt * 128;
  const int tid  = threadIdx.x;
  const int wid  = tid >> 6;
  const int lane = tid & 63;
  const int wm   = (wid >> 1) * (BM / 2);
  const int wn   = (wid & 1) * 64;
  const int lrow = lane & 15;
  const int lkc  = lane >> 4;

  f32x4 acc[MF][4] = {};

  for (int k0 = 0; k0 < K; k0 += 64) {
#pragma unroll
    for (int i = 0; i < MF; ++i) {
      const int ci = tid + i * 256;
      const int r = ci >> 3, cc = ci & 7;
      const int gc = cc ^ (r & 7);
      __builtin_amdgcn_global_load_lds(
          (const __attribute__((address_space(1))) void*)(A + (size_t)(m0 + r) * K + k0 + gc * 8),
          (__attribute__((address_space(3))) void*)(&As[ci * 8]), 16, 0, 0);
    }
#pragma unroll
    for (int i = 0; i < 4; ++i) {
      const int ci = tid + i * 256;
      const int r = ci >> 3, cc = ci & 7;
      const int gc = cc ^ (r & 7);
      __builtin_amdgcn_global_load_lds(
          (const __attribute__((address_space(1))) void*)(B + (size_t)(n0 + r) * K + k0 + gc * 8),
          (__attribute__((address_space(3))) void*)(&Bs[ci * 8]), 16, 0, 0);
    }
    __syncthreads();   // compiler emits s_waitcnt vmcnt(0) before s_barrier

    bf16x8 af[MF][2], bf[4][2];
#pragma unroll
    for (int m = 0; m < MF; ++m)
#pragma unroll
      for (int kk = 0; kk < 2; ++kk) {
        const int row = wm + m * 16 + lrow;
        const int c = kk * 4 + lkc;
        af[m][kk] = *reinterpret_cast<const bf16x8*>(
            &As[row * 64 + ((c ^ (row & 7)) * 8)]);
      }
#pragma unroll
    for (int n = 0; n < 4; ++n)
#pragma unroll
      for (int kk = 0; kk < 2; ++kk) {
        const int row = wn + n * 16 + lrow;
        const int c = kk * 4 + lkc;
        bf[n][kk] = *reinterpret_cast<const bf16x8*>(
            &Bs[row * 64 + ((c ^ (row & 7)) * 8)]);
      }
#pragma unroll
    for (int kk = 0; kk < 2; ++kk)
#pragma unroll
      for (int m = 0; m < MF; ++m)
#pragma unroll
        for (int n = 0; n < 4; ++n)
          acc[m][n] = __builtin_amdgcn_mfma_f32_16x16x32_bf16(af[m][kk], bf[n][kk], acc[m][n], 0, 0, 0);
    __syncthreads();
  }

  // C/D layout: col = lane&15, row = (lane>>4)*4 + reg  [m89/m91 verified]
#pragma unroll
  for (int m = 0; m < MF; ++m) {
#pragma unroll
    for (int n = 0; n < 4; ++n) {
      const int col = n0 + wn + n * 16 + lrow;
      if (col < Nc) {
#pragma unroll
        for (int v = 0; v < 4; ++v) {
          const int row = m0 + wm + m * 16 + (lane >> 4) * 4 + v;
          if (row < Mc) {
            const size_t idx = (size_t)row * ldc + col;
            float val = acc[m][n][v];
            if constexpr (OUT16) {
              ((unsigned short*)Cv)[idx] = f2b(val);
            } else {
              if (RES) val += res[idx];
              ((float*)Cv)[idx] = val;
            }
          }
        }
      }
    }
  }
}

// ---------------------------------------------------------------------------
// Pipelined bf16 GEMM, depth 3 — out_proj. fp32 out + residual.
// ---------------------------------------------------------------------------
template<int BM, bool RES>
__global__ __launch_bounds__(256, 2) void gemm_pipe3(
    const unsigned short* __restrict__ A, const unsigned short* __restrict__ B,
    float* __restrict__ C, const float* __restrict__ res,
    int K, int Mc, int Nc, int ldc, int nm, int nn, int grp) {
  constexpr int MF = BM / 32;
  constexpr int LPS = MF + 4;
  __shared__ __align__(16) unsigned short As[3][BM * 64];
  __shared__ __align__(16) unsigned short Bs[3][128 * 64];
  int mt, nt;
  tile_map(blockIdx.x, nm * nn, nm, nn, grp, mt, nt);
  const int m0 = mt * BM;
  const int n0 = nt * 128;
  const int tid  = threadIdx.x;
  const int wid  = tid >> 6;
  const int lane = tid & 63;
  const int wm   = (wid >> 1) * (BM / 2);
  const int wn   = (wid & 1) * 64;
  const int lrow = lane & 15;
  const int lkc  = lane >> 4;

  auto stage = [&](int buf, int k0) {
#pragma unroll
    for (int i = 0; i < MF; ++i) {
      const int ci = tid + i * 256;
      const int r = ci >> 3, cc = ci & 7;
      const int gc = cc ^ (r & 7);
      __builtin_amdgcn_global_load_lds(
          (const __attribute__((address_space(1))) void*)(A + (size_t)(m0 + r) * K + k0 + gc * 8),
          (__attribute__((address_space(3))) void*)(&As[buf][ci * 8]), 16, 0, 0);
    }
#pragma unroll
    for (int i = 0; i < 4; ++i) {
      const int ci = tid + i * 256;
      const int r = ci >> 3, cc = ci & 7;
      const int gc = cc ^ (r & 7);
      __builtin_amdgcn_global_load_lds(
          (const __attribute__((address_space(1))) void*)(B + (size_t)(n0 + r) * K + k0 + gc * 8),
          (__attribute__((address_space(3))) void*)(&Bs[buf][ci * 8]), 16, 0, 0);
    }
  };

  f32x4 acc[MF][4] = {};
  const int nsteps = K >> 6;

  stage(0, 0);
  if (nsteps > 1) stage(1, 64);
  if (nsteps > 2) stage(2, 128);
  if (nsteps > 2)      asm volatile("s_waitcnt vmcnt(%0)" :: "n"(2 * LPS) : "memory");
  else if (nsteps > 1) asm volatile("s_waitcnt vmcnt(%0)" :: "n"(LPS) : "memory");
  else                 asm volatile("s_waitcnt vmcnt(0)" ::: "memory");
  __builtin_amdgcn_s_barrier();
  __builtin_amdgcn_sched_barrier(0);

  int cur = 0;
  for (int t = 0; t < nsteps; ++t) {
    bf16x8 af[MF][2], bf[4][2];
#pragma unroll
    for (int m = 0; m < MF; ++m)
#pragma unroll
      for (int kk = 0; kk < 2; ++kk) {
        const int row = wm + m * 16 + lrow;
        const int c = kk * 4 + lkc;
        af[m][kk] = *reinterpret_cast<const bf16x8*>(
            &As[cur][row * 64 + ((c ^ (row & 7)) * 8)]);
      }
#pragma unroll
    for (int n = 0; n < 4; ++n)
#pragma unroll
      for (int kk = 0; kk < 2; ++kk) {
        const int row = wn + n * 16 + lrow;
        const int c = kk * 4 + lkc;
        bf[n][kk] = *reinterpret_cast<const bf16x8*>(
            &Bs[cur][row * 64 + ((c ^ (row & 7)) * 8)]);
      }
    asm volatile("s_waitcnt lgkmcnt(0)" ::: "memory");
    __builtin_amdgcn_sched_barrier(0);
    __builtin_amdgcn_s_barrier();
    if (t + 3 < nsteps) stage(cur, (t + 3) * 64);
    __builtin_amdgcn_s_setprio(1);
#pragma unroll
    for (int kk = 0; kk < 2; ++kk)
#pragma unroll
      for (int m = 0; m < MF; ++m)
#pragma unroll
        for (int n = 0; n < 4; ++n)
          acc[m][n] = __builtin_amdgcn_mfma_f32_16x16x32_bf16(af[m][kk], bf[n][kk], acc[m][n], 0, 0, 0);
    __builtin_amdgcn_s_setprio(0);
    if (t + 1 < nsteps) {
      if (t + 3 < nsteps)      asm volatile("s_waitcnt vmcnt(%0)" :: "n"(2 * LPS) : "memory");
      else if (t + 2 < nsteps) asm volatile("s_waitcnt vmcnt(%0)" :: "n"(LPS) : "memory");
      else                     asm volatile("s_waitcnt vmcnt(0)" ::: "memory");
      __builtin_amdgcn_sched_barrier(0);
      __builtin_amdgcn_s_barrier();
    }
    cur = (cur == 2) ? 0 : cur + 1;
  }

#pragma unroll
  for (int m = 0; m < MF; ++m) {
#pragma unroll
    for (int n = 0; n < 4; ++n) {
      const int col = n0 + wn + n * 16 + lrow;
      if (col < Nc) {
#pragma unroll
        for (int v = 0; v < 4; ++v) {
          const int row = m0 + wm + m * 16 + (lane >> 4) * 4 + v;
          if (row < Mc) {
            const size_t idx = (size_t)row * ldc + col;
            float val = acc[m][n][v];
            if (RES) val += res[idx];
            C[idx] = val;
          }
        }
      }
    }
  }
}

// ---------------------------------------------------------------------------
// causal depthwise conv(K=4) + SiLU; softplus(dt+bias). proj is bf16.
// ---------------------------------------------------------------------------
__global__ __launch_bounds__(256) void conv_silu_dt(
    const unsigned short* __restrict__ proj, const float* __restrict__ conv_w,
    const float* __restrict__ conv_b, const float* __restrict__ dt_bias,
    unsigned short* __restrict__ xs, float* __restrict__ BC,
    unsigned short* __restrict__ BTb, unsigned short* __restrict__ Bsb,
    unsigned short* __restrict__ Cbb, float* __restrict__ dtc) {
  const int cch = blockIdx.x * 256 + threadIdx.x;
  const int l0 = blockIdx.y * 16;
  if (cch < 4352) {
    const float4 w = *reinterpret_cast<const float4*>(conv_w + (size_t)cch * 4);
    const float b = conv_b[cch];
    const unsigned short* pcol = proj + 4096 + cch;
    float w0, w1, w2;
    w0 = (l0 >= 3) ? b2f(pcol[(size_t)(l0 - 3) * 8512]) : 0.0f;
    w1 = (l0 >= 2) ? b2f(pcol[(size_t)(l0 - 2) * 8512]) : 0.0f;
    w2 = (l0 >= 1) ? b2f(pcol[(size_t)(l0 - 1) * 8512]) : 0.0f;
#pragma unroll
    for (int i = 0; i < 16; ++i) {
      const int l = l0 + i;
      const float cur = b2f(pcol[(size_t)l * 8512]);
      float acc = b + w0 * w.x + w1 * w.y + w2 * w.z + cur * w.w;
      w0 = w1; w1 = w2; w2 = cur;
      acc = acc / (1.0f + __expf(-acc));   // silu
      if (cch < 4096) {
        xs[(size_t)l * 4096 + cch] = f2b(acc);
      } else {
        BC[(size_t)l * 256 + (cch - 4096)] = acc;
        if (cch < 4224) {                  // B channels
          const int n = cch - 4096;
          const unsigned short bb = f2b(acc);
          BTb[((size_t)((l >> 8) * 128) + n) * 256 + (l & 255)] = bb;
          Bsb[(size_t)l * 128 + n] = bb;
        } else {                            // C channels
          const int n = cch - 4224;
          Cbb[(size_t)l * 128 + n] = f2b(acc);
        }
      }
    }
  } else if (cch < 4416) {
    const int hh = cch - 4352;
    const float bias = dt_bias[hh];
#pragma unroll
    for (int i = 0; i < 16; ++i) {
      const int l = l0 + i;
      const float v = b2f(proj[(size_t)l * 8512 + 8448 + hh]) + bias;
      dtc[(size_t)l * 64 + hh] = (v > 20.0f) ? v : log1pf(expf(v));
    }
  }
}

// ---------------------------------------------------------------------------
// FUSED: blocks [0,512) = dA-scan + MFMA chunk states (statesT bf16 out);
// blocks [512,544) = CB = C@B^T MFMA (8 waves, block tile 64l x 256s).
// ---------------------------------------------------------------------------
__global__ __launch_bounds__(512) void ssd_states_scan_cb(
    const unsigned short* __restrict__ xs, const unsigned short* __restrict__ BTb,
    const float* __restrict__ dtc, const float* __restrict__ A_log,
    float* __restrict__ dAc, float* __restrict__ cdec,
    unsigned short* __restrict__ statesT,
    const unsigned short* __restrict__ Cbb, const unsigned short* __restrict__ Bsb,
    float* __restrict__ CB) {
  const int tid = threadIdx.x;
  const int lane = tid & 63;
  const int w = tid >> 6;

  if (blockIdx.x >= 512) {
    const int bx2 = blockIdx.x - 512;
    const int c = bx2 >> 2;
    const int l0 = (bx2 & 3) * 64;
    const int wm = (w >> 1) * 16;
    const int wn = (w & 1) * 128;
    const int lrow = lane & 15;
    const int lk = (lane >> 4) * 8;
    const size_t arow = (size_t)(c * 256 + l0 + wm + lrow) * 128;
    f32x4 acc[8] = {};
#pragma unroll
    for (int kk = 0; kk < 4; ++kk) {
      bf16x8 av = *reinterpret_cast<const bf16x8*>(Cbb + arow + kk * 32 + lk);
#pragma unroll
      for (int nf = 0; nf < 8; ++nf) {
        bf16x8 bv = *reinterpret_cast<const bf16x8*>(
            Bsb + (size_t)(c * 256 + wn + nf * 16 + lrow) * 128 + kk * 32 + lk);
        acc[nf] = __builtin_amdgcn_mfma_f32_16x16x32_bf16(av, bv, acc[nf], 0, 0, 0);
      }
    }
#pragma unroll
    for (int nf = 0; nf < 8; ++nf) {
      const int s = wn + nf * 16 + lrow;
#pragma unroll
      for (int v = 0; v < 4; ++v) {
        const int l = l0 + wm + (lane >> 4) * 4 + v;
        CB[((size_t)(c * 256) + l) * 256 + s] = acc[nf][v];
      }
    }
    return;
  }

  // ---- states block
  const int bx = blockIdx.x;              // c*64 + h
  const int c = bx >> 6, h = bx & 63;
  __shared__ __align__(16) unsigned short xwT[64 * 264];
  __shared__ float dAL[256], dtL[256];

  if (tid < 256) dtL[tid] = dtc[(size_t)(c * 256 + tid) * 64 + h];
  const float Ah = -__expf(A_log[h]);
  __syncthreads();
  if (tid < 256) dAL[tid] = dtL[tid] * Ah;
  __syncthreads();
  for (int off = 1; off < 256; off <<= 1) {
    const float t = (tid < 256 && tid >= off) ? dAL[tid - off] : 0.0f;
    __syncthreads();
    if (tid < 256) dAL[tid] += t;
    __syncthreads();
  }
  if (tid < 256) dAc[(size_t)bx * 256 + tid] = dAL[tid];
  if (tid == 255) cdec[bx] = __expf(dAL[255]);
  if (tid < 256) dtL[tid] = __expf(dAL[255] - dAL[tid]) * dtL[tid];  // wLs
  __syncthreads();

#pragma unroll
  for (int it = 0; it < 4; ++it) {
    const int gid = it * 512 + tid;
    const int p = gid & 63;
    const int s0 = (gid >> 6) * 8;
    bf16x8 r;
#pragma unroll
    for (int k = 0; k < 8; ++k)
      r[k] = (__bf16)(b2f(xs[(size_t)(c * 256 + s0 + k) * 4096 + h * 64 + p]) * dtL[s0 + k]);
    *reinterpret_cast<bf16x8*>(&xwT[p * 264 + s0]) = r;
  }
  __syncthreads();

  const int pb = (w & 3) * 16;
  const int nb = (w >> 2) * 64;
  const int kcol = (lane >> 4) * 8;
  f32x4 acc[4] = {};
  for (int k = 0; k < 8; ++k) {
    bf16x8 av = *reinterpret_cast<const bf16x8*>(&xwT[(pb + (lane & 15)) * 264 + k * 32 + kcol]);
#pragma unroll
    for (int nf = 0; nf < 4; ++nf) {
      bf16x8 bv = *reinterpret_cast<const bf16x8*>(
          BTb + ((size_t)(c * 128) + nb + nf * 16 + (lane & 15)) * 256 + k * 32 + kcol);
      acc[nf] = __builtin_amdgcn_mfma_f32_16x16x32_bf16(av, bv, acc[nf], 0, 0, 0);
    }
  }
  const int rb = (lane >> 4) * 4;
#pragma unroll
  for (int nf = 0; nf < 4; ++nf) {
    const int n = nb + nf * 16 + (lane & 15);
#pragma unroll
    for (int v = 0; v < 4; ++v) {
      const int p = pb + rb + v;
      statesT[(size_t)bx * 8192 + p * 128 + n] = f2b(acc[nf][v]);
    }
  }
}

// ---------------------------------------------------------------------------
// inter-chunk scan: statesT bf16 in, prev-state (BEFORE chunk) bf16 out.
// ---------------------------------------------------------------------------
__global__ void ssd_scan(const unsigned short* __restrict__ statesT,
                         unsigned short* __restrict__ prevb,
                         const float* __restrict__ cdec) {
  const int i = blockIdx.x * 256 + threadIdx.x;   // < 64*8192
  const int h = i >> 13;
  const int r = i & 8191;
  float carry = 0.0f;
#pragma unroll
  for (int c = 0; c < 8; ++c) {
    const size_t idx = ((size_t)(c * 64 + h)) * 8192 + r;
    const float st = b2f(statesT[idx]);
    prevb[idx] = f2b(carry);
    carry = carry * cdec[c * 64 + h] + st;
  }
}

// ---------------------------------------------------------------------------
// MFMA Y_diag + Y_off + D*xs -> y (bf16, in-place over xs).
// ---------------------------------------------------------------------------
__global__ __launch_bounds__(512) void ssd_diag_off(
    const unsigned short* xs, const float* __restrict__ BC,
    const float* __restrict__ dtc, const float* __restrict__ dAc,
    const float* __restrict__ CB, const unsigned short* __restrict__ prevb,
    const float* __restrict__ Dp, unsigned short* y) {
  const int bx = blockIdx.x;              // c*64 + h
  const int c = bx >> 6, h = bx & 63;
  __shared__ __align__(16) unsigned short xsT[64 * 264];
  __shared__ float dAL[256], dtL[256], vdt[256];
  const int tid = threadIdx.x;
  const int lane = tid & 63;
  const int w = tid >> 6;

  if (tid < 256) {
    dAL[tid] = dAc[(size_t)bx * 256 + tid];
    dtL[tid] = dtc[(size_t)(c * 256 + tid) * 64 + h];
  }
  __syncthreads();
  if (tid < 256) vdt[tid] = __expf(dAL[tid | 31] - dAL[tid]) * dtL[tid];
#pragma unroll
  for (int it = 0; it < 4; ++it) {
    const int gid = it * 512 + tid;
    const int p = gid & 63;
    const int s0 = (gid >> 6) * 8;
    unsigned short r[8];
#pragma unroll
    for (int k = 0; k < 8; ++k)
      r[k] = xs[(size_t)(c * 256 + s0 + k) * 4096 + h * 64 + p];
    *reinterpret_cast<uint4*>(&xsT[p * 264 + s0]) = *reinterpret_cast<uint4*>(r);
  }
  __syncthreads();

  const int l1 = w * 32 + (lane & 15);
  const int l2 = l1 + 16;
  const int kcol = (lane >> 4) * 8;
  const float dA1 = dAL[l1], dA2 = dAL[l2];
  const float* CBr1 = CB + ((size_t)(c * 256) + l1) * 256;
  const float* CBr2 = CB + ((size_t)(c * 256) + l2) * 256;
  f32x4 acc[2][4] = {};

  for (int j = 0; j < w; ++j) {
    const int s0 = j * 32 + kcol;
    float cb1[8], cb2[8];
    *reinterpret_cast<float4*>(&cb1[0]) = *reinterpret_cast<const float4*>(CBr1 + s0);
    *reinterpret_cast<float4*>(&cb1[4]) = *reinterpret_cast<const float4*>(CBr1 + s0 + 4);
    *reinterpret_cast<float4*>(&cb2[0]) = *reinterpret_cast<const float4*>(CBr2 + s0);
    *reinterpret_cast<float4*>(&cb2[4]) = *reinterpret_cast<const float4*>(CBr2 + s0 + 4);
    const float a = dAL[j * 32 + 31];
    const float u1 = __expf(dA1 - a), u2 = __expf(dA2 - a);
    float m1[8], m2[8];
#pragma unroll
    for (int t = 0; t < 8; ++t) {
      const float uv = vdt[s0 + t];
      m1[t] = cb1[t] * (u1 * uv);
      m2[t] = cb2[t] * (u2 * uv);
    }
    bf16x8 a1 = pack8(m1), a2 = pack8(m2);
#pragma unroll
    for (int nf = 0; nf < 4; ++nf) {
      bf16x8 bv = *reinterpret_cast<const bf16x8*>(
          &xsT[(nf * 16 + (lane & 15)) * 264 + j * 32 + kcol]);
      acc[0][nf] = __builtin_amdgcn_mfma_f32_16x16x32_bf16(a1, bv, acc[0][nf], 0, 0, 0);
      acc[1][nf] = __builtin_amdgcn_mfma_f32_16x16x32_bf16(a2, bv, acc[1][nf], 0, 0, 0);
    }
  }
  {
    const int s0 = w * 32 + kcol;
    float cb1[8], cb2[8];
    *reinterpret_cast<float4*>(&cb1[0]) = *reinterpret_cast<const float4*>(CBr1 + s0);
    *reinterpret_cast<float4*>(&cb1[4]) = *reinterpret_cast<const float4*>(CBr1 + s0 + 4);
    *reinterpret_cast<float4*>(&cb2[0]) = *reinterpret_cast<const float4*>(CBr2 + s0);
    *reinterpret_cast<float4*>(&cb2[4]) = *reinterpret_cast<const float4*>(CBr2 + s0 + 4);
    float m1[8], m2[8];
#pragma unroll
    for (int t = 0; t < 8; ++t) {
      const int s = s0 + t;
      const float e1 = __expf(fminf(dA1 - dAL[s], 0.0f)) * dtL[s];
      const float e2 = __expf(fminf(dA2 - dAL[s], 0.0f)) * dtL[s];
      m1[t] = (s <= l1) ? cb1[t] * e1 : 0.0f;
      m2[t] = (s <= l2) ? cb2[t] * e2 : 0.0f;
    }
    bf16x8 a1 = pack8(m1), a2 = pack8(m2);
#pragma unroll
    for (int nf = 0; nf < 4; ++nf) {
      bf16x8 bv = *reinterpret_cast<const bf16x8*>(
          &xsT[(nf * 16 + (lane & 15)) * 264 + w * 32 + kcol]);
      acc[0][nf] = __builtin_amdgcn_mfma_f32_16x16x32_bf16(a1, bv, acc[0][nf], 0, 0, 0);
      acc[1][nf] = __builtin_amdgcn_mfma_f32_16x16x32_bf16(a2, bv, acc[1][nf], 0, 0, 0);
    }
  }
  {
    const float eA1 = __expf(dA1), eA2 = __expf(dA2);
    const float* Cr1 = BC + ((size_t)(c * 256) + l1) * 256 + 128;
    const float* Cr2 = BC + ((size_t)(c * 256) + l2) * 256 + 128;
    const unsigned short* pv = prevb + (size_t)bx * 8192;
#pragma unroll
    for (int q = 0; q < 4; ++q) {
      const int n0 = q * 32 + kcol;
      float c1[8], c2[8];
      *reinterpret_cast<float4*>(&c1[0]) = *reinterpret_cast<const float4*>(Cr1 + n0);
      *reinterpret_cast<float4*>(&c1[4]) = *reinterpret_cast<const float4*>(Cr1 + n0 + 4);
      *reinterpret_cast<float4*>(&c2[0]) = *reinterpret_cast<const float4*>(Cr2 + n0);
      *reinterpret_cast<float4*>(&c2[4]) = *reinterpret_cast<const float4*>(Cr2 + n0 + 4);
      float m1[8], m2[8];
#pragma unroll
      for (int t = 0; t < 8; ++t) { m1[t] = c1[t] * eA1; m2[t] = c2[t] * eA2; }
      bf16x8 a1 = pack8(m1), a2 = pack8(m2);
#pragma unroll
      for (int nf = 0; nf < 4; ++nf) {
        bf16x8 bv = *reinterpret_cast<const bf16x8*>(
            pv + (size_t)(nf * 16 + (lane & 15)) * 128 + n0);
        acc[0][nf] = __builtin_amdgcn_mfma_f32_16x16x32_bf16(a1, bv, acc[0][nf], 0, 0, 0);
        acc[1][nf] = __builtin_amdgcn_mfma_f32_16x16x32_bf16(a2, bv, acc[1][nf], 0, 0, 0);
      }
    }
  }
  const float Dh = Dp[h];
  const int rb = (lane >> 4) * 4;
#pragma unroll
  for (int mf = 0; mf < 2; ++mf) {
#pragma unroll
    for (int nf = 0; nf < 4; ++nf) {
      const int p = nf * 16 + (lane & 15);
#pragma unroll
      for (int v = 0; v < 4; ++v) {
        const int l = w * 32 + mf * 16 + rb + v;
        y[(size_t)(c * 256 + l) * 4096 + h * 64 + p] =
            f2b(acc[mf][nf][v] + Dh * b2f(xsT[p * 264 + l]));
      }
    }
  }
}

// ---------------------------------------------------------------------------
// gated RMSNorm: y2 = rmsnorm(y * silu(z)) * norm_w -> bf16. y, proj bf16.
// ---------------------------------------------------------------------------
__global__ __launch_bounds__(256) void gated_rmsnorm(
    const unsigned short* __restrict__ y, const unsigned short* __restrict__ proj,
    const float* __restrict__ nw, unsigned short* __restrict__ y2) {
  const int row = blockIdx.x;
  const unsigned short* yr = y + (size_t)row * 4096;
  const unsigned short* zr = proj + (size_t)row * 8512;
  const int base = threadIdx.x * 16;
  unsigned short yu[16], zu[16];
  *reinterpret_cast<uint4*>(&yu[0]) = *reinterpret_cast<const uint4*>(yr + base);
  *reinterpret_cast<uint4*>(&yu[8]) = *reinterpret_cast<const uint4*>(yr + base + 8);
  *reinterpret_cast<uint4*>(&zu[0]) = *reinterpret_cast<const uint4*>(zr + base);
  *reinterpret_cast<uint4*>(&zu[8]) = *reinterpret_cast<const uint4*>(zr + base + 8);
  float g[16];
  float ss = 0.0f;
#pragma unroll
  for (int j = 0; j < 16; ++j) {
    const float zf = b2f(zu[j]);
    const float a = b2f(yu[j]) * (zf / (1.0f + expf(-zf)));
    g[j] = a;
    ss += a * a;
  }
  __shared__ float red[4];
#pragma unroll
  for (int off = 32; off > 0; off >>= 1) ss += __shfl_xor(ss, off);
  if ((threadIdx.x & 63) == 0) red[threadIdx.x >> 6] = ss;
  __syncthreads();
  ss = red[0] + red[1] + red[2] + red[3];
  const float scale = rsqrtf(ss * (1.0f / 4096.0f) + 1e-5f);
#pragma unroll
  for (int j = 0; j < 16; j += 4) {
    ushort4 o;
    o.x = f2b(g[j]   * scale * nw[base + j]);
    o.y = f2b(g[j+1] * scale * nw[base + j + 1]);
    o.z = f2b(g[j+2] * scale * nw[base + j + 2]);
    o.w = f2b(g[j+3] * scale * nw[base + j + 3]);
    *reinterpret_cast<ushort4*>(y2 + (size_t)row * 4096 + base + j) = o;
  }
}

// ---------------------------------------------------------------------------
extern "C" void kernel_launch(void* const* d_in, const int* in_sizes, int n_in,
                              void* d_out, int out_size, void* d_ws, size_t ws_size,
                              hipStream_t stream) {
  const float* x       = (const float*)d_in[0];
  const float* rms_w   = (const float*)d_in[1];
  const float* W_in    = (const float*)d_in[2];
  const float* conv_w  = (const float*)d_in[3];
  const float* conv_b  = (const float*)d_in[4];
  const float* dt_bias = (const float*)d_in[5];
  const float* A_log   = (const float*)d_in[6];
  const float* Dp      = (const float*)d_in[7];
  const float* norm_w  = (const float*)d_in[8];
  const float* W_out   = (const float*)d_in[9];
  float* out = (float*)d_out;

  char* ws = (char*)d_ws;
  size_t off = 0;
  auto alloc = [&](size_t bytes) {
    void* p = ws + off;
    off += (bytes + 255) & ~(size_t)255;
    return p;
  };
  unsigned short* Wb_in  = (unsigned short*)alloc((size_t)8576 * 2048 * 2);
  unsigned short* Wb_out = (unsigned short*)alloc((size_t)2048 * 4096 * 2);
  unsigned short* hbuf   = (unsigned short*)alloc((size_t)2112 * 2048 * 2); // M-pad
  unsigned short* proj   = (unsigned short*)alloc((size_t)2048 * 8512 * 2); // bf16
  unsigned short* xsbuf  = (unsigned short*)alloc((size_t)2048 * 4096 * 2); // xs->y bf16
  float* BCbuf  = (float*)alloc((size_t)2048 * 256 * 4);
  unsigned short* BTb = (unsigned short*)alloc((size_t)8 * 128 * 256 * 2);
  unsigned short* Bsb = (unsigned short*)alloc((size_t)2048 * 128 * 2);
  unsigned short* Cbb = (unsigned short*)alloc((size_t)2048 * 128 * 2);
  float* dtcbuf = (float*)alloc((size_t)2048 * 64 * 4);
  float* dAcbuf = (float*)alloc((size_t)512 * 256 * 4);
  float* cdec   = (float*)alloc((size_t)512 * 4);
  float* CBbuf  = (float*)alloc((size_t)8 * 256 * 256 * 4);
  unsigned short* statesT = (unsigned short*)alloc((size_t)512 * 64 * 128 * 2); // bf16
  unsigned short* y2 = Wb_in;              // dead after in_proj GEMM
  unsigned short* prevb = hbuf;            // dead after in_proj GEMM

  (void)in_sizes; (void)n_in; (void)out_size; (void)ws_size;

  // 0. prep: weight conversions + input RMSNorm in one launch
  const long cvtChunks = ((long)8576 * 2048 + (long)2048 * 4096) / 4;
  const int ncvt = (int)((cvtChunks + 255) / 256);
  prep<<<ncvt + 2112, 256, 0, stream>>>(W_in, Wb_in, W_out, Wb_out,
                                        x, rms_w, hbuf, ncvt);

  // 1. in_proj: proj[2048,8512] bf16 = h @ W_in^T
  //    192x128 single-buffered, 40 KB LDS -> 4 blocks/CU, 737 blocks resident
  gemm_sb<192, false, true><<<11 * 67, 256, 0, stream>>>(
      hbuf, Wb_in, proj, nullptr, 2048, 2048, 8512, 8512, 11, 67, 4);

  // 2. conv + SiLU + softplus(dt); xs bf16
  conv_silu_dt<<<dim3(18, 128), 256, 0, stream>>>(proj, conv_w, conv_b, dt_bias,
                                                  xsbuf, BCbuf, BTb, Bsb, Cbb,
                                                  dtcbuf);

  // 3. fused dA-scan + MFMA states (bf16 out) + CB MFMA
  ssd_states_scan_cb<<<544, 512, 0, stream>>>(xsbuf, BTb, dtcbuf, A_log,
                                              dAcbuf, cdec, statesT,
                                              Cbb, Bsb, CBbuf);

  // 4. inter-chunk recurrence -> prev states (bf16)
  ssd_scan<<<2048, 256, 0, stream>>>(statesT, prevb, cdec);

  // 5. MFMA Y_diag + Y_off + D*xs -> y bf16 (in-place over xs)
  ssd_diag_off<<<512, 512, 0, stream>>>(xsbuf, BCbuf, dtcbuf, dAcbuf, CBbuf,
                                        prevb, Dp, xsbuf);

  // 6. gated RMSNorm -> bf16
  gated_rmsnorm<<<2048, 256, 0, stream>>>(xsbuf, proj, norm_w, y2);

  // 7. out_proj + residual -> d_out  (depth-3 pipe, 64x128 tiles)
  gemm_pipe3<64, true><<<32 * 16, 256, 0, stream>>>(y2, Wb_out, out, x,
                                                    4096, 2048, 2048, 2048,
                                                    32, 16, 4);
}

// Round 16
// 262.356 us; speedup vs baseline: 1.2130x; 1.2130x over previous
//
#include <hip/hip_runtime.h>
#include <stdint.h>

// ---------------------------------------------------------------------------
// FalconMamba2 SSM decoder layer, MI355X (gfx950) — round 16
// Revert to round-13 configuration (best measured: 263 us). Round 15's
// single-buffer 192-tile spilled acc to scratch (launch_bounds(256,4) caps
// VGPR at 64 < the 96-reg accumulator) — that grid cell is infeasible.
// in_proj: gemm_pipe<192> depth-2. out_proj: gemm_pipe3<64>. statesT fp32.
// ---------------------------------------------------------------------------

typedef __bf16 bf16x8 __attribute__((ext_vector_type(8)));
typedef float  f32x4  __attribute__((ext_vector_type(4)));

#define DEVFN __device__ __forceinline__

DEVFN unsigned short f2b(float f) {
  uint32_t u = __builtin_bit_cast(uint32_t, f);
  u += 0x7fffu + ((u >> 16) & 1u);          // round-to-nearest-even
  return (unsigned short)(u >> 16);
}
DEVFN float b2f(unsigned short u) {
  uint32_t x = (uint32_t)u << 16;
  return __builtin_bit_cast(float, x);
}
DEVFN bf16x8 pack8(const float (&m)[8]) {
  bf16x8 r;
#pragma unroll
  for (int t = 0; t < 8; ++t) r[t] = (__bf16)m[t];
  return r;
}

// bijective XCD swizzle (m204) + GROUP-major supertiling
DEVFN void tile_map(int bid, int nwg, int nm, int nn, int grp, int& mt, int& nt) {
  const int q = nwg >> 3, r = nwg & 7;
  const int xcd = bid & 7, lid = bid >> 3;
  const int wg = (xcd < r ? xcd * (q + 1) : r * (q + 1) + (xcd - r) * q) + lid;
  const int per = grp * nn;
  const int g = wg / per;
  const int rem = wg - g * per;
  const int lim = nm - g * grp;
  const int gm = lim < grp ? lim : grp;
  mt = g * grp + rem % gm;
  nt = rem / gm;
}

// ---------------------------------------------------------------------------
// prep: blocks [0, NCVT) convert both weight matrices fp32->bf16 (padded);
// blocks [NCVT, NCVT+2112) compute input RMSNorm rows (rows>=2048 zero-pad).
// ---------------------------------------------------------------------------
__global__ __launch_bounds__(256) void prep(
    const float* __restrict__ W_in, unsigned short* __restrict__ Wb_in,
    const float* __restrict__ W_out, unsigned short* __restrict__ Wb_out,
    const float* __restrict__ x, const float* __restrict__ rms_w,
    unsigned short* __restrict__ h, int ncvt) {
  const long d1 = (long)8576 * 2048, s1 = (long)8512 * 2048;
  const long d2 = (long)2048 * 4096;
  if (blockIdx.x < (unsigned)ncvt) {
    long i = ((long)blockIdx.x * 256 + threadIdx.x) * 4;
    const float* s; unsigned short* d; long srcE;
    if (i < d1) { s = W_in; d = Wb_in; srcE = s1; }
    else {
      i -= d1;
      if (i >= d2) return;
      s = W_out; d = Wb_out; srcE = d2;
    }
    ushort4 o;
    if (i < srcE) {
      float4 v = *reinterpret_cast<const float4*>(s + i);
      o.x = f2b(v.x); o.y = f2b(v.y); o.z = f2b(v.z); o.w = f2b(v.w);
    } else {
      o.x = 0; o.y = 0; o.z = 0; o.w = 0;
    }
    *reinterpret_cast<ushort4*>(d + i) = o;
    return;
  }
  // ---- RMSNorm rows
  const int row = blockIdx.x - ncvt;
  const int base = threadIdx.x * 8;
  if (row >= 2048) {
    ushort4 z = {0, 0, 0, 0};
    *reinterpret_cast<ushort4*>(h + (size_t)row * 2048 + base)     = z;
    *reinterpret_cast<ushort4*>(h + (size_t)row * 2048 + base + 4) = z;
    return;
  }
  const float* xr = x + (size_t)row * 2048;
  float4 v0 = *reinterpret_cast<const float4*>(xr + base);
  float4 v1 = *reinterpret_cast<const float4*>(xr + base + 4);
  float ss = v0.x*v0.x + v0.y*v0.y + v0.z*v0.z + v0.w*v0.w
           + v1.x*v1.x + v1.y*v1.y + v1.z*v1.z + v1.w*v1.w;
  __shared__ float red[4];
#pragma unroll
  for (int off = 32; off > 0; off >>= 1) ss += __shfl_xor(ss, off);
  if ((threadIdx.x & 63) == 0) red[threadIdx.x >> 6] = ss;
  __syncthreads();
  ss = red[0] + red[1] + red[2] + red[3];
  const float scale = rsqrtf(ss * (1.0f / 2048.0f) + 1e-5f);
  float vals[8] = {v0.x, v0.y, v0.z, v0.w, v1.x, v1.y, v1.z, v1.w};
  unsigned short o[8];
#pragma unroll
  for (int j = 0; j < 8; ++j) o[j] = f2b(vals[j] * scale * rms_w[base + j]);
  ushort4 a, b;
  a.x = o[0]; a.y = o[1]; a.z = o[2]; a.w = o[3];
  b.x = o[4]; b.y = o[5]; b.z = o[6]; b.w = o[7];
  *reinterpret_cast<ushort4*>(h + (size_t)row * 2048 + base)     = a;
  *reinterpret_cast<ushort4*>(h + (size_t)row * 2048 + base + 4) = b;
}

// ---------------------------------------------------------------------------
// Pipelined bf16 GEMM (depth 2) — in_proj. OUT16: C written bf16.
// ---------------------------------------------------------------------------
template<int BM, bool RES, bool OUT16>
__global__ __launch_bounds__(256, 2) void gemm_pipe(
    const unsigned short* __restrict__ A, const unsigned short* __restrict__ B,
    void* __restrict__ Cv, const float* __restrict__ res,
    int K, int Mc, int Nc, int ldc, int nm, int nn, int grp) {
  constexpr int MF = BM / 32;
  __shared__ __align__(16) unsigned short As[2][BM * 64];
  __shared__ __align__(16) unsigned short Bs[2][128 * 64];
  int mt, nt;
  tile_map(blockIdx.x, nm * nn, nm, nn, grp, mt, nt);
  const int m0 = mt * BM;
  const int n0 = nt * 128;
  const int tid  = threadIdx.x;
  const int wid  = tid >> 6;
  const int lane = tid & 63;
  const int wm   = (wid >> 1) * (BM / 2);
  const int wn   = (wid & 1) * 64;
  const int lrow = lane & 15;
  const int lkc  = lane >> 4;

  auto stageA = [&](int buf, int k0) {
#pragma unroll
    for (int i = 0; i < MF; ++i) {
      const int ci = tid + i * 256;
      const int r = ci >> 3, cc = ci & 7;
      const int gc = cc ^ (r & 7);
      __builtin_amdgcn_global_load_lds(
          (const __attribute__((address_space(1))) void*)(A + (size_t)(m0 + r) * K + k0 + gc * 8),
          (__attribute__((address_space(3))) void*)(&As[buf][ci * 8]), 16, 0, 0);
    }
  };
  auto stageB = [&](int buf, int k0) {
#pragma unroll
    for (int i = 0; i < 4; ++i) {
      const int ci = tid + i * 256;
      const int r = ci >> 3, cc = ci & 7;
      const int gc = cc ^ (r & 7);
      __builtin_amdgcn_global_load_lds(
          (const __attribute__((address_space(1))) void*)(B + (size_t)(n0 + r) * K + k0 + gc * 8),
          (__attribute__((address_space(3))) void*)(&Bs[buf][ci * 8]), 16, 0, 0);
    }
  };

  f32x4 acc[MF][4] = {};
  const int nsteps = K >> 6;

  stageA(0, 0); stageB(0, 0);
  if (nsteps > 1) { stageA(1, 64); stageB(1, 64); }
  if (nsteps > 1) asm volatile("s_waitcnt vmcnt(%0)" :: "n"(MF + 4) : "memory");
  else            asm volatile("s_waitcnt vmcnt(0)" ::: "memory");
  __builtin_amdgcn_s_barrier();
  __builtin_amdgcn_sched_barrier(0);

  int cur = 0;
  for (int t = 0; t < nsteps; ++t) {
    bf16x8 af[MF][2], bf[4][2];
#pragma unroll
    for (int m = 0; m < MF; ++m)
#pragma unroll
      for (int kk = 0; kk < 2; ++kk) {
        const int row = wm + m * 16 + lrow;
        const int c = kk * 4 + lkc;
        af[m][kk] = *reinterpret_cast<const bf16x8*>(
            &As[cur][row * 64 + ((c ^ (row & 7)) * 8)]);
      }
#pragma unroll
    for (int n = 0; n < 4; ++n)
#pragma unroll
      for (int kk = 0; kk < 2; ++kk) {
        const int row = wn + n * 16 + lrow;
        const int c = kk * 4 + lkc;
        bf[n][kk] = *reinterpret_cast<const bf16x8*>(
            &Bs[cur][row * 64 + ((c ^ (row & 7)) * 8)]);
      }
    asm volatile("s_waitcnt lgkmcnt(0)" ::: "memory");
    __builtin_amdgcn_sched_barrier(0);
    __builtin_amdgcn_s_barrier();
    if (t + 2 < nsteps) { stageA(cur, (t + 2) * 64); stageB(cur, (t + 2) * 64); }
    __builtin_amdgcn_s_setprio(1);
#pragma unroll
    for (int kk = 0; kk < 2; ++kk)
#pragma unroll
      for (int m = 0; m < MF; ++m)
#pragma unroll
        for (int n = 0; n < 4; ++n)
          acc[m][n] = __builtin_amdgcn_mfma_f32_16x16x32_bf16(af[m][kk], bf[n][kk], acc[m][n], 0, 0, 0);
    __builtin_amdgcn_s_setprio(0);
    if (t + 1 < nsteps) {
      if (t + 2 < nsteps) asm volatile("s_waitcnt vmcnt(%0)" :: "n"(MF + 4) : "memory");
      else                asm volatile("s_waitcnt vmcnt(0)" ::: "memory");
      __builtin_amdgcn_sched_barrier(0);
      __builtin_amdgcn_s_barrier();
    }
    cur ^= 1;
  }

#pragma unroll
  for (int m = 0; m < MF; ++m) {
#pragma unroll
    for (int n = 0; n < 4; ++n) {
      const int col = n0 + wn + n * 16 + lrow;
      if (col < Nc) {
#pragma unroll
        for (int v = 0; v < 4; ++v) {
          const int row = m0 + wm + m * 16 + (lane >> 4) * 4 + v;
          if (row < Mc) {
            const size_t idx = (size_t)row * ldc + col;
            float val = acc[m][n][v];
            if constexpr (OUT16) {
              ((unsigned short*)Cv)[idx] = f2b(val);
            } else {
              if (RES) val += res[idx];
              ((float*)Cv)[idx] = val;
            }
          }
        }
      }
    }
  }
}

// ---------------------------------------------------------------------------
// Pipelined bf16 GEMM, depth 3 — out_proj. fp32 out + residual.
// ---------------------------------------------------------------------------
template<int BM, bool RES>
__global__ __launch_bounds__(256, 2) void gemm_pipe3(
    const unsigned short* __restrict__ A, const unsigned short* __restrict__ B,
    float* __restrict__ C, const float* __restrict__ res,
    int K, int Mc, int Nc, int ldc, int nm, int nn, int grp) {
  constexpr int MF = BM / 32;
  constexpr int LPS = MF + 4;
  __shared__ __align__(16) unsigned short As[3][BM * 64];
  __shared__ __align__(16) unsigned short Bs[3][128 * 64];
  int mt, nt;
  tile_map(blockIdx.x, nm * nn, nm, nn, grp, mt, nt);
  const int m0 = mt * BM;
  const int n0 = nt * 128;
  const int tid  = threadIdx.x;
  const int wid  = tid >> 6;
  const int lane = tid & 63;
  const int wm   = (wid >> 1) * (BM / 2);
  const int wn   = (wid & 1) * 64;
  const int lrow = lane & 15;
  const int lkc  = lane >> 4;

  auto stage = [&](int buf, int k0) {
#pragma unroll
    for (int i = 0; i < MF; ++i) {
      const int ci = tid + i * 256;
      const int r = ci >> 3, cc = ci & 7;
      const int gc = cc ^ (r & 7);
      __builtin_amdgcn_global_load_lds(
          (const __attribute__((address_space(1))) void*)(A + (size_t)(m0 + r) * K + k0 + gc * 8),
          (__attribute__((address_space(3))) void*)(&As[buf][ci * 8]), 16, 0, 0);
    }
#pragma unroll
    for (int i = 0; i < 4; ++i) {
      const int ci = tid + i * 256;
      const int r = ci >> 3, cc = ci & 7;
      const int gc = cc ^ (r & 7);
      __builtin_amdgcn_global_load_lds(
          (const __attribute__((address_space(1))) void*)(B + (size_t)(n0 + r) * K + k0 + gc * 8),
          (__attribute__((address_space(3))) void*)(&Bs[buf][ci * 8]), 16, 0, 0);
    }
  };

  f32x4 acc[MF][4] = {};
  const int nsteps = K >> 6;

  stage(0, 0);
  if (nsteps > 1) stage(1, 64);
  if (nsteps > 2) stage(2, 128);
  if (nsteps > 2)      asm volatile("s_waitcnt vmcnt(%0)" :: "n"(2 * LPS) : "memory");
  else if (nsteps > 1) asm volatile("s_waitcnt vmcnt(%0)" :: "n"(LPS) : "memory");
  else                 asm volatile("s_waitcnt vmcnt(0)" ::: "memory");
  __builtin_amdgcn_s_barrier();
  __builtin_amdgcn_sched_barrier(0);

  int cur = 0;
  for (int t = 0; t < nsteps; ++t) {
    bf16x8 af[MF][2], bf[4][2];
#pragma unroll
    for (int m = 0; m < MF; ++m)
#pragma unroll
      for (int kk = 0; kk < 2; ++kk) {
        const int row = wm + m * 16 + lrow;
        const int c = kk * 4 + lkc;
        af[m][kk] = *reinterpret_cast<const bf16x8*>(
            &As[cur][row * 64 + ((c ^ (row & 7)) * 8)]);
      }
#pragma unroll
    for (int n = 0; n < 4; ++n)
#pragma unroll
      for (int kk = 0; kk < 2; ++kk) {
        const int row = wn + n * 16 + lrow;
        const int c = kk * 4 + lkc;
        bf[n][kk] = *reinterpret_cast<const bf16x8*>(
            &Bs[cur][row * 64 + ((c ^ (row & 7)) * 8)]);
      }
    asm volatile("s_waitcnt lgkmcnt(0)" ::: "memory");
    __builtin_amdgcn_sched_barrier(0);
    __builtin_amdgcn_s_barrier();
    if (t + 3 < nsteps) stage(cur, (t + 3) * 64);
    __builtin_amdgcn_s_setprio(1);
#pragma unroll
    for (int kk = 0; kk < 2; ++kk)
#pragma unroll
      for (int m = 0; m < MF; ++m)
#pragma unroll
        for (int n = 0; n < 4; ++n)
          acc[m][n] = __builtin_amdgcn_mfma_f32_16x16x32_bf16(af[m][kk], bf[n][kk], acc[m][n], 0, 0, 0);
    __builtin_amdgcn_s_setprio(0);
    if (t + 1 < nsteps) {
      if (t + 3 < nsteps)      asm volatile("s_waitcnt vmcnt(%0)" :: "n"(2 * LPS) : "memory");
      else if (t + 2 < nsteps) asm volatile("s_waitcnt vmcnt(%0)" :: "n"(LPS) : "memory");
      else                     asm volatile("s_waitcnt vmcnt(0)" ::: "memory");
      __builtin_amdgcn_sched_barrier(0);
      __builtin_amdgcn_s_barrier();
    }
    cur = (cur == 2) ? 0 : cur + 1;
  }

#pragma unroll
  for (int m = 0; m < MF; ++m) {
#pragma unroll
    for (int n = 0; n < 4; ++n) {
      const int col = n0 + wn + n * 16 + lrow;
      if (col < Nc) {
#pragma unroll
        for (int v = 0; v < 4; ++v) {
          const int row = m0 + wm + m * 16 + (lane >> 4) * 4 + v;
          if (row < Mc) {
            const size_t idx = (size_t)row * ldc + col;
            float val = acc[m][n][v];
            if (RES) val += res[idx];
            C[idx] = val;
          }
        }
      }
    }
  }
}

// ---------------------------------------------------------------------------
// causal depthwise conv(K=4) + SiLU; softplus(dt+bias). proj is bf16.
// ---------------------------------------------------------------------------
__global__ __launch_bounds__(256) void conv_silu_dt(
    const unsigned short* __restrict__ proj, const float* __restrict__ conv_w,
    const float* __restrict__ conv_b, const float* __restrict__ dt_bias,
    unsigned short* __restrict__ xs, float* __restrict__ BC,
    unsigned short* __restrict__ BTb, unsigned short* __restrict__ Bsb,
    unsigned short* __restrict__ Cbb, float* __restrict__ dtc) {
  const int cch = blockIdx.x * 256 + threadIdx.x;
  const int l0 = blockIdx.y * 16;
  if (cch < 4352) {
    const float4 w = *reinterpret_cast<const float4*>(conv_w + (size_t)cch * 4);
    const float b = conv_b[cch];
    const unsigned short* pcol = proj + 4096 + cch;
    float w0, w1, w2;
    w0 = (l0 >= 3) ? b2f(pcol[(size_t)(l0 - 3) * 8512]) : 0.0f;
    w1 = (l0 >= 2) ? b2f(pcol[(size_t)(l0 - 2) * 8512]) : 0.0f;
    w2 = (l0 >= 1) ? b2f(pcol[(size_t)(l0 - 1) * 8512]) : 0.0f;
#pragma unroll
    for (int i = 0; i < 16; ++i) {
      const int l = l0 + i;
      const float cur = b2f(pcol[(size_t)l * 8512]);
      float acc = b + w0 * w.x + w1 * w.y + w2 * w.z + cur * w.w;
      w0 = w1; w1 = w2; w2 = cur;
      acc = acc / (1.0f + __expf(-acc));   // silu
      if (cch < 4096) {
        xs[(size_t)l * 4096 + cch] = f2b(acc);
      } else {
        BC[(size_t)l * 256 + (cch - 4096)] = acc;
        if (cch < 4224) {                  // B channels
          const int n = cch - 4096;
          const unsigned short bb = f2b(acc);
          BTb[((size_t)((l >> 8) * 128) + n) * 256 + (l & 255)] = bb;
          Bsb[(size_t)l * 128 + n] = bb;
        } else {                            // C channels
          const int n = cch - 4224;
          Cbb[(size_t)l * 128 + n] = f2b(acc);
        }
      }
    }
  } else if (cch < 4416) {
    const int hh = cch - 4352;
    const float bias = dt_bias[hh];
#pragma unroll
    for (int i = 0; i < 16; ++i) {
      const int l = l0 + i;
      const float v = b2f(proj[(size_t)l * 8512 + 8448 + hh]) + bias;
      dtc[(size_t)l * 64 + hh] = (v > 20.0f) ? v : log1pf(expf(v));
    }
  }
}

// ---------------------------------------------------------------------------
// FUSED: blocks [0,512) = dA-scan + MFMA chunk states (statesT fp32 out);
// blocks [512,544) = CB = C@B^T MFMA (8 waves, block tile 64l x 256s).
// ---------------------------------------------------------------------------
__global__ __launch_bounds__(512) void ssd_states_scan_cb(
    const unsigned short* __restrict__ xs, const unsigned short* __restrict__ BTb,
    const float* __restrict__ dtc, const float* __restrict__ A_log,
    float* __restrict__ dAc, float* __restrict__ cdec,
    float* __restrict__ statesT,
    const unsigned short* __restrict__ Cbb, const unsigned short* __restrict__ Bsb,
    float* __restrict__ CB) {
  const int tid = threadIdx.x;
  const int lane = tid & 63;
  const int w = tid >> 6;

  if (blockIdx.x >= 512) {
    const int bx2 = blockIdx.x - 512;
    const int c = bx2 >> 2;
    const int l0 = (bx2 & 3) * 64;
    const int wm = (w >> 1) * 16;
    const int wn = (w & 1) * 128;
    const int lrow = lane & 15;
    const int lk = (lane >> 4) * 8;
    const size_t arow = (size_t)(c * 256 + l0 + wm + lrow) * 128;
    f32x4 acc[8] = {};
#pragma unroll
    for (int kk = 0; kk < 4; ++kk) {
      bf16x8 av = *reinterpret_cast<const bf16x8*>(Cbb + arow + kk * 32 + lk);
#pragma unroll
      for (int nf = 0; nf < 8; ++nf) {
        bf16x8 bv = *reinterpret_cast<const bf16x8*>(
            Bsb + (size_t)(c * 256 + wn + nf * 16 + lrow) * 128 + kk * 32 + lk);
        acc[nf] = __builtin_amdgcn_mfma_f32_16x16x32_bf16(av, bv, acc[nf], 0, 0, 0);
      }
    }
#pragma unroll
    for (int nf = 0; nf < 8; ++nf) {
      const int s = wn + nf * 16 + lrow;
#pragma unroll
      for (int v = 0; v < 4; ++v) {
        const int l = l0 + wm + (lane >> 4) * 4 + v;
        CB[((size_t)(c * 256) + l) * 256 + s] = acc[nf][v];
      }
    }
    return;
  }

  // ---- states block
  const int bx = blockIdx.x;              // c*64 + h
  const int c = bx >> 6, h = bx & 63;
  __shared__ __align__(16) unsigned short xwT[64 * 264];
  __shared__ float dAL[256], dtL[256];

  if (tid < 256) dtL[tid] = dtc[(size_t)(c * 256 + tid) * 64 + h];
  const float Ah = -__expf(A_log[h]);
  __syncthreads();
  if (tid < 256) dAL[tid] = dtL[tid] * Ah;
  __syncthreads();
  for (int off = 1; off < 256; off <<= 1) {
    const float t = (tid < 256 && tid >= off) ? dAL[tid - off] : 0.0f;
    __syncthreads();
    if (tid < 256) dAL[tid] += t;
    __syncthreads();
  }
  if (tid < 256) dAc[(size_t)bx * 256 + tid] = dAL[tid];
  if (tid == 255) cdec[bx] = __expf(dAL[255]);
  if (tid < 256) dtL[tid] = __expf(dAL[255] - dAL[tid]) * dtL[tid];  // wLs
  __syncthreads();

#pragma unroll
  for (int it = 0; it < 4; ++it) {
    const int gid = it * 512 + tid;
    const int p = gid & 63;
    const int s0 = (gid >> 6) * 8;
    bf16x8 r;
#pragma unroll
    for (int k = 0; k < 8; ++k)
      r[k] = (__bf16)(b2f(xs[(size_t)(c * 256 + s0 + k) * 4096 + h * 64 + p]) * dtL[s0 + k]);
    *reinterpret_cast<bf16x8*>(&xwT[p * 264 + s0]) = r;
  }
  __syncthreads();

  const int pb = (w & 3) * 16;
  const int nb = (w >> 2) * 64;
  const int kcol = (lane >> 4) * 8;
  f32x4 acc[4] = {};
  for (int k = 0; k < 8; ++k) {
    bf16x8 av = *reinterpret_cast<const bf16x8*>(&xwT[(pb + (lane & 15)) * 264 + k * 32 + kcol]);
#pragma unroll
    for (int nf = 0; nf < 4; ++nf) {
      bf16x8 bv = *reinterpret_cast<const bf16x8*>(
          BTb + ((size_t)(c * 128) + nb + nf * 16 + (lane & 15)) * 256 + k * 32 + kcol);
      acc[nf] = __builtin_amdgcn_mfma_f32_16x16x32_bf16(av, bv, acc[nf], 0, 0, 0);
    }
  }
  const int rb = (lane >> 4) * 4;
#pragma unroll
  for (int nf = 0; nf < 4; ++nf) {
    const int n = nb + nf * 16 + (lane & 15);
#pragma unroll
    for (int v = 0; v < 4; ++v) {
      const int p = pb + rb + v;
      statesT[(size_t)bx * 8192 + p * 128 + n] = acc[nf][v];
    }
  }
}

// ---------------------------------------------------------------------------
// inter-chunk scan: emits prev-state (BEFORE chunk) as bf16 [c][h][p][n]
// ---------------------------------------------------------------------------
__global__ void ssd_scan(const float* __restrict__ statesT,
                         unsigned short* __restrict__ prevb,
                         const float* __restrict__ cdec) {
  const int i = blockIdx.x * 256 + threadIdx.x;   // < 64*8192
  const int h = i >> 13;
  const int r = i & 8191;
  float carry = 0.0f;
#pragma unroll
  for (int c = 0; c < 8; ++c) {
    const size_t idx = ((size_t)(c * 64 + h)) * 8192 + r;
    const float st = statesT[idx];
    prevb[idx] = f2b(carry);
    carry = carry * cdec[c * 64 + h] + st;
  }
}

// ---------------------------------------------------------------------------
// MFMA Y_diag + Y_off + D*xs -> y (bf16, in-place over xs).
// ---------------------------------------------------------------------------
__global__ __launch_bounds__(512) void ssd_diag_off(
    const unsigned short* xs, const float* __restrict__ BC,
    const float* __restrict__ dtc, const float* __restrict__ dAc,
    const float* __restrict__ CB, const unsigned short* __restrict__ prevb,
    const float* __restrict__ Dp, unsigned short* y) {
  const int bx = blockIdx.x;              // c*64 + h
  const int c = bx >> 6, h = bx & 63;
  __shared__ __align__(16) unsigned short xsT[64 * 264];
  __shared__ float dAL[256], dtL[256], vdt[256];
  const int tid = threadIdx.x;
  const int lane = tid & 63;
  const int w = tid >> 6;

  if (tid < 256) {
    dAL[tid] = dAc[(size_t)bx * 256 + tid];
    dtL[tid] = dtc[(size_t)(c * 256 + tid) * 64 + h];
  }
  __syncthreads();
  if (tid < 256) vdt[tid] = __expf(dAL[tid | 31] - dAL[tid]) * dtL[tid];
#pragma unroll
  for (int it = 0; it < 4; ++it) {
    const int gid = it * 512 + tid;
    const int p = gid & 63;
    const int s0 = (gid >> 6) * 8;
    unsigned short r[8];
#pragma unroll
    for (int k = 0; k < 8; ++k)
      r[k] = xs[(size_t)(c * 256 + s0 + k) * 4096 + h * 64 + p];
    *reinterpret_cast<uint4*>(&xsT[p * 264 + s0]) = *reinterpret_cast<uint4*>(r);
  }
  __syncthreads();

  const int l1 = w * 32 + (lane & 15);
  const int l2 = l1 + 16;
  const int kcol = (lane >> 4) * 8;
  const float dA1 = dAL[l1], dA2 = dAL[l2];
  const float* CBr1 = CB + ((size_t)(c * 256) + l1) * 256;
  const float* CBr2 = CB + ((size_t)(c * 256) + l2) * 256;
  f32x4 acc[2][4] = {};

  for (int j = 0; j < w; ++j) {
    const int s0 = j * 32 + kcol;
    float cb1[8], cb2[8];
    *reinterpret_cast<float4*>(&cb1[0]) = *reinterpret_cast<const float4*>(CBr1 + s0);
    *reinterpret_cast<float4*>(&cb1[4]) = *reinterpret_cast<const float4*>(CBr1 + s0 + 4);
    *reinterpret_cast<float4*>(&cb2[0]) = *reinterpret_cast<const float4*>(CBr2 + s0);
    *reinterpret_cast<float4*>(&cb2[4]) = *reinterpret_cast<const float4*>(CBr2 + s0 + 4);
    const float a = dAL[j * 32 + 31];
    const float u1 = __expf(dA1 - a), u2 = __expf(dA2 - a);
    float m1[8], m2[8];
#pragma unroll
    for (int t = 0; t < 8; ++t) {
      const float uv = vdt[s0 + t];
      m1[t] = cb1[t] * (u1 * uv);
      m2[t] = cb2[t] * (u2 * uv);
    }
    bf16x8 a1 = pack8(m1), a2 = pack8(m2);
#pragma unroll
    for (int nf = 0; nf < 4; ++nf) {
      bf16x8 bv = *reinterpret_cast<const bf16x8*>(
          &xsT[(nf * 16 + (lane & 15)) * 264 + j * 32 + kcol]);
      acc[0][nf] = __builtin_amdgcn_mfma_f32_16x16x32_bf16(a1, bv, acc[0][nf], 0, 0, 0);
      acc[1][nf] = __builtin_amdgcn_mfma_f32_16x16x32_bf16(a2, bv, acc[1][nf], 0, 0, 0);
    }
  }
  {
    const int s0 = w * 32 + kcol;
    float cb1[8], cb2[8];
    *reinterpret_cast<float4*>(&cb1[0]) = *reinterpret_cast<const float4*>(CBr1 + s0);
    *reinterpret_cast<float4*>(&cb1[4]) = *reinterpret_cast<const float4*>(CBr1 + s0 + 4);
    *reinterpret_cast<float4*>(&cb2[0]) = *reinterpret_cast<const float4*>(CBr2 + s0);
    *reinterpret_cast<float4*>(&cb2[4]) = *reinterpret_cast<const float4*>(CBr2 + s0 + 4);
    float m1[8], m2[8];
#pragma unroll
    for (int t = 0; t < 8; ++t) {
      const int s = s0 + t;
      const float e1 = __expf(fminf(dA1 - dAL[s], 0.0f)) * dtL[s];
      const float e2 = __expf(fminf(dA2 - dAL[s], 0.0f)) * dtL[s];
      m1[t] = (s <= l1) ? cb1[t] * e1 : 0.0f;
      m2[t] = (s <= l2) ? cb2[t] * e2 : 0.0f;
    }
    bf16x8 a1 = pack8(m1), a2 = pack8(m2);
#pragma unroll
    for (int nf = 0; nf < 4; ++nf) {
      bf16x8 bv = *reinterpret_cast<const bf16x8*>(
          &xsT[(nf * 16 + (lane & 15)) * 264 + w * 32 + kcol]);
      acc[0][nf] = __builtin_amdgcn_mfma_f32_16x16x32_bf16(a1, bv, acc[0][nf], 0, 0, 0);
      acc[1][nf] = __builtin_amdgcn_mfma_f32_16x16x32_bf16(a2, bv, acc[1][nf], 0, 0, 0);
    }
  }
  {
    const float eA1 = __expf(dA1), eA2 = __expf(dA2);
    const float* Cr1 = BC + ((size_t)(c * 256) + l1) * 256 + 128;
    const float* Cr2 = BC + ((size_t)(c * 256) + l2) * 256 + 128;
    const unsigned short* pv = prevb + (size_t)bx * 8192;
#pragma unroll
    for (int q = 0; q < 4; ++q) {
      const int n0 = q * 32 + kcol;
      float c1[8], c2[8];
      *reinterpret_cast<float4*>(&c1[0]) = *reinterpret_cast<const float4*>(Cr1 + n0);
      *reinterpret_cast<float4*>(&c1[4]) = *reinterpret_cast<const float4*>(Cr1 + n0 + 4);
      *reinterpret_cast<float4*>(&c2[0]) = *reinterpret_cast<const float4*>(Cr2 + n0);
      *reinterpret_cast<float4*>(&c2[4]) = *reinterpret_cast<const float4*>(Cr2 + n0 + 4);
      float m1[8], m2[8];
#pragma unroll
      for (int t = 0; t < 8; ++t) { m1[t] = c1[t] * eA1; m2[t] = c2[t] * eA2; }
      bf16x8 a1 = pack8(m1), a2 = pack8(m2);
#pragma unroll
      for (int nf = 0; nf < 4; ++nf) {
        bf16x8 bv = *reinterpret_cast<const bf16x8*>(
            pv + (size_t)(nf * 16 + (lane & 15)) * 128 + n0);
        acc[0][nf] = __builtin_amdgcn_mfma_f32_16x16x32_bf16(a1, bv, acc[0][nf], 0, 0, 0);
        acc[1][nf] = __builtin_amdgcn_mfma_f32_16x16x32_bf16(a2, bv, acc[1][nf], 0, 0, 0);
      }
    }
  }
  const float Dh = Dp[h];
  const int rb = (lane >> 4) * 4;
#pragma unroll
  for (int mf = 0; mf < 2; ++mf) {
#pragma unroll
    for (int nf = 0; nf < 4; ++nf) {
      const int p = nf * 16 + (lane & 15);
#pragma unroll
      for (int v = 0; v < 4; ++v) {
        const int l = w * 32 + mf * 16 + rb + v;
        y[(size_t)(c * 256 + l) * 4096 + h * 64 + p] =
            f2b(acc[mf][nf][v] + Dh * b2f(xsT[p * 264 + l]));
      }
    }
  }
}

// ---------------------------------------------------------------------------
// gated RMSNorm: y2 = rmsnorm(y * silu(z)) * norm_w -> bf16. y, proj bf16.
// ---------------------------------------------------------------------------
__global__ __launch_bounds__(256) void gated_rmsnorm(
    const unsigned short* __restrict__ y, const unsigned short* __restrict__ proj,
    const float* __restrict__ nw, unsigned short* __restrict__ y2) {
  const int row = blockIdx.x;
  const unsigned short* yr = y + (size_t)row * 4096;
  const unsigned short* zr = proj + (size_t)row * 8512;
  const int base = threadIdx.x * 16;
  unsigned short yu[16], zu[16];
  *reinterpret_cast<uint4*>(&yu[0]) = *reinterpret_cast<const uint4*>(yr + base);
  *reinterpret_cast<uint4*>(&yu[8]) = *reinterpret_cast<const uint4*>(yr + base + 8);
  *reinterpret_cast<uint4*>(&zu[0]) = *reinterpret_cast<const uint4*>(zr + base);
  *reinterpret_cast<uint4*>(&zu[8]) = *reinterpret_cast<const uint4*>(zr + base + 8);
  float g[16];
  float ss = 0.0f;
#pragma unroll
  for (int j = 0; j < 16; ++j) {
    const float zf = b2f(zu[j]);
    const float a = b2f(yu[j]) * (zf / (1.0f + expf(-zf)));
    g[j] = a;
    ss += a * a;
  }
  __shared__ float red[4];
#pragma unroll
  for (int off = 32; off > 0; off >>= 1) ss += __shfl_xor(ss, off);
  if ((threadIdx.x & 63) == 0) red[threadIdx.x >> 6] = ss;
  __syncthreads();
  ss = red[0] + red[1] + red[2] + red[3];
  const float scale = rsqrtf(ss * (1.0f / 4096.0f) + 1e-5f);
#pragma unroll
  for (int j = 0; j < 16; j += 4) {
    ushort4 o;
    o.x = f2b(g[j]   * scale * nw[base + j]);
    o.y = f2b(g[j+1] * scale * nw[base + j + 1]);
    o.z = f2b(g[j+2] * scale * nw[base + j + 2]);
    o.w = f2b(g[j+3] * scale * nw[base + j + 3]);
    *reinterpret_cast<ushort4*>(y2 + (size_t)row * 4096 + base + j) = o;
  }
}

// ---------------------------------------------------------------------------
extern "C" void kernel_launch(void* const* d_in, const int* in_sizes, int n_in,
                              void* d_out, int out_size, void* d_ws, size_t ws_size,
                              hipStream_t stream) {
  const float* x       = (const float*)d_in[0];
  const float* rms_w   = (const float*)d_in[1];
  const float* W_in    = (const float*)d_in[2];
  const float* conv_w  = (const float*)d_in[3];
  const float* conv_b  = (const float*)d_in[4];
  const float* dt_bias = (const float*)d_in[5];
  const float* A_log   = (const float*)d_in[6];
  const float* Dp      = (const float*)d_in[7];
  const float* norm_w  = (const float*)d_in[8];
  const float* W_out   = (const float*)d_in[9];
  float* out = (float*)d_out;

  char* ws = (char*)d_ws;
  size_t off = 0;
  auto alloc = [&](size_t bytes) {
    void* p = ws + off;
    off += (bytes + 255) & ~(size_t)255;
    return p;
  };
  unsigned short* Wb_in  = (unsigned short*)alloc((size_t)8576 * 2048 * 2);
  unsigned short* Wb_out = (unsigned short*)alloc((size_t)2048 * 4096 * 2);
  unsigned short* hbuf   = (unsigned short*)alloc((size_t)2112 * 2048 * 2); // M-pad
  unsigned short* proj   = (unsigned short*)alloc((size_t)2048 * 8512 * 2); // bf16
  unsigned short* xsbuf  = (unsigned short*)alloc((size_t)2048 * 4096 * 2); // xs->y bf16
  float* BCbuf  = (float*)alloc((size_t)2048 * 256 * 4);
  unsigned short* BTb = (unsigned short*)alloc((size_t)8 * 128 * 256 * 2);
  unsigned short* Bsb = (unsigned short*)alloc((size_t)2048 * 128 * 2);
  unsigned short* Cbb = (unsigned short*)alloc((size_t)2048 * 128 * 2);
  float* dtcbuf = (float*)alloc((size_t)2048 * 64 * 4);
  float* dAcbuf = (float*)alloc((size_t)512 * 256 * 4);
  float* cdec   = (float*)alloc((size_t)512 * 4);
  float* CBbuf  = (float*)alloc((size_t)8 * 256 * 256 * 4);
  float* statesT = (float*)alloc((size_t)512 * 64 * 128 * 4);
  unsigned short* y2 = Wb_in;              // dead after in_proj GEMM
  unsigned short* prevb = hbuf;            // dead after in_proj GEMM

  (void)in_sizes; (void)n_in; (void)out_size; (void)ws_size;

  // 0. prep: weight conversions + input RMSNorm in one launch
  const long cvtChunks = ((long)8576 * 2048 + (long)2048 * 4096) / 4;
  const int ncvt = (int)((cvtChunks + 255) / 256);
  prep<<<ncvt + 2112, 256, 0, stream>>>(W_in, Wb_in, W_out, Wb_out,
                                        x, rms_w, hbuf, ncvt);

  // 1. in_proj: proj[2048,8512] bf16 = h @ W_in^T  (192x128 tiles, depth-2)
  gemm_pipe<192, false, true><<<11 * 67, 256, 0, stream>>>(
      hbuf, Wb_in, proj, nullptr, 2048, 2048, 8512, 8512, 11, 67, 4);

  // 2. conv + SiLU + softplus(dt); xs bf16
  conv_silu_dt<<<dim3(18, 128), 256, 0, stream>>>(proj, conv_w, conv_b, dt_bias,
                                                  xsbuf, BCbuf, BTb, Bsb, Cbb,
                                                  dtcbuf);

  // 3. fused dA-scan + MFMA states + CB MFMA
  ssd_states_scan_cb<<<544, 512, 0, stream>>>(xsbuf, BTb, dtcbuf, A_log,
                                              dAcbuf, cdec, statesT,
                                              Cbb, Bsb, CBbuf);

  // 4. inter-chunk recurrence -> prev states (bf16)
  ssd_scan<<<2048, 256, 0, stream>>>(statesT, prevb, cdec);

  // 5. MFMA Y_diag + Y_off + D*xs -> y bf16 (in-place over xs)
  ssd_diag_off<<<512, 512, 0, stream>>>(xsbuf, BCbuf, dtcbuf, dAcbuf, CBbuf,
                                        prevb, Dp, xsbuf);

  // 6. gated RMSNorm -> bf16
  gated_rmsnorm<<<2048, 256, 0, stream>>>(xsbuf, proj, norm_w, y2);

  // 7. out_proj + residual -> d_out  (depth-3 pipe, 64x128 tiles)
  gemm_pipe3<64, true><<<32 * 16, 256, 0, stream>>>(y2, Wb_out, out, x,
                                                    4096, 2048, 2048, 2048,
                                                    32, 16, 4);
}